// Round 4
// baseline (494.588 us; speedup 1.0000x reference)
//
#include <hip/hip_runtime.h>

// Fused attention prefill, bf16 MFMA pipeline.
// ws layout (ushort units, 1M = 1024*1024):
//   xb 0..4M | wqkvb 4M..10M | wob 10M..14M | qkvb 14M..20M | qb 20M..24M
//   kb 24M..25M | vt 25M..26M | yb 26M..30M | obuf 30M..(+33.5MB) | lbuf
// kb/vt layout: MFMA-fragment order. Per 64x64 tile:
//   addr = tile_base + (p*64 + lane)*8 ushorts, p = c*4 + j (j = B-operand
//   16-row group, c = K-chunk of 32), lane = quad*16 + col.
// vt columns are sigma-permuted key positions: pos p holds key
//   u = (p&3)*16 + (p>>2), matching attn's P store order.
// attn v12: v11's balanced strip pairs {y,127-y} + K-PARITY SPLIT: block
// (kvh, y, khalf) does only tiles t%2==khalf. Every wave = 16.5-17 tile
// units (balanced by construction); 1024 blocks = 4/CU = 4 waves/SIMD
// (v8-v11 all sat at 2/SIMD and all stalled at ~41 us, VALUBusy 36%).
// Partial (o,l) in f32 buffers; merge_norm sums halves + normalizes.

typedef __attribute__((ext_vector_type(8))) __bf16 bf16x8;
typedef __attribute__((ext_vector_type(4))) float f32x4;

#define S_LEN 2048
#define DIMN  2048
#define NH    32
#define NKV   8
#define HD    64
#define QKVF  3072

__device__ __forceinline__ ushort f2bf(float f) {
  union { float f; unsigned u; } v; v.f = f;
  unsigned r = v.u + 0x7fffu + ((v.u >> 16) & 1u);
  return (ushort)(r >> 16);
}
__device__ __forceinline__ unsigned pack_bf2_rz(float a, float b) {
  union { float f; unsigned u; } va, vb; va.f = a; vb.f = b;
  return (va.u >> 16) | (vb.u & 0xffff0000u);
}
__device__ __forceinline__ float bf2f(ushort u) {
  union { unsigned u; float f; } v; v.u = ((unsigned)u) << 16;
  return v.f;
}
__device__ __forceinline__ void gld_lds16(const void* g, void* l) {
  __builtin_amdgcn_global_load_lds(
      (const __attribute__((address_space(1))) unsigned int*)g,
      (__attribute__((address_space(3))) unsigned int*)l, 16, 0, 0);
}

// ---------------- f32 -> bf16 conversion (x, [wq;wk;wv], wo) ----------------
__global__ __launch_bounds__(256) void convert_all(
    const float* __restrict__ x, const float* __restrict__ wq,
    const float* __restrict__ wk, const float* __restrict__ wv,
    const float* __restrict__ wo, ushort* __restrict__ xb,
    ushort* __restrict__ wqkvb, ushort* __restrict__ wob) {
  const size_t NX = 4u * 1024 * 1024;
  const size_t NK = 1024 * 1024;
  size_t idx = ((size_t)blockIdx.x * 256 + threadIdx.x) * 4;
  const float* src; ushort* dst;
  if (idx < NX)                { src = x  + idx;                  dst = xb + idx; }
  else if (idx < 2 * NX)       { src = wq + (idx - NX);           dst = wqkvb + (idx - NX); }
  else if (idx < 2 * NX + NK)  { src = wk + (idx - 2 * NX);       dst = wqkvb + NX + (idx - 2 * NX); }
  else if (idx < 2 * NX + 2*NK){ src = wv + (idx - 2 * NX - NK);  dst = wqkvb + NX + NK + (idx - 2 * NX - NK); }
  else                         { src = wo + (idx - 2 * NX - 2*NK);dst = wob + (idx - 2 * NX - 2 * NK); }
  float4 v = *(const float4*)src;
  ushort4 o; o.x = f2bf(v.x); o.y = f2bf(v.y); o.z = f2bf(v.z); o.w = f2bf(v.w);
  *(ushort4*)dst = o;
}

// ---------------- GEMM: dbuf LDS + XOR bank swizzle, tile (BM x BN) ---------
template <int OUT_BF16, int BM, int BN>
__global__ __launch_bounds__(256) void gemm_bt(
    const ushort* __restrict__ A, const ushort* __restrict__ B,
    void* __restrict__ Cv, int M, int N, int K) {
  constexpr int IB = BM / 32;
  constexpr int JB = BN / 32;
  constexpr int NGA = BM / 8;
  constexpr int GPW = (BM + BN) / 32;
  __shared__ __align__(16) ushort As[2][BM * 64];
  __shared__ __align__(16) ushort Bs[2][BN * 64];
  const int n0 = blockIdx.x * BN, m0 = blockIdx.y * BM;
  const int t = threadIdx.x;
  const int lane = t & 63, wave = t >> 6;
  const int wm = (wave >> 1) * (BM / 2), wn = (wave & 1) * (BN / 2);
  const int col = lane & 15, quad = lane >> 4;
  const int sw = col & 7;
  const int lrow = lane >> 3;
  const int scol = ((lane & 7) ^ lrow) * 8;
  f32x4 acc[IB][JB] = {};

  auto stage = [&](int b, int kk) {
#pragma unroll
    for (int c = 0; c < GPW; ++c) {
      int g = wave * GPW + c;
      if (g < NGA)
        gld_lds16(&A[(size_t)(m0 + g * 8 + lrow) * K + kk + scol], &As[b][g * 8 * 64]);
      else
        gld_lds16(&B[(size_t)(n0 + (g - NGA) * 8 + lrow) * K + kk + scol],
                  &Bs[b][(g - NGA) * 8 * 64]);
    }
  };

  stage(0, 0);
  __syncthreads();
  for (int kk = 0; kk < K; kk += 64) {
    const int b = (kk >> 6) & 1;
    if (kk + 64 < K) stage(b ^ 1, kk + 64);
#pragma unroll
    for (int c = 0; c < 2; ++c) {
      const int chs = ((c * 4 + quad) ^ sw) * 8;
      bf16x8 af[IB], bfr[JB];
#pragma unroll
      for (int i = 0; i < IB; ++i)
        af[i] = *(const bf16x8*)&As[b][(wm + i * 16 + col) * 64 + chs];
#pragma unroll
      for (int j = 0; j < JB; ++j)
        bfr[j] = *(const bf16x8*)&Bs[b][(wn + j * 16 + col) * 64 + chs];
#pragma unroll
      for (int i = 0; i < IB; ++i)
#pragma unroll
        for (int j = 0; j < JB; ++j)
          acc[i][j] = __builtin_amdgcn_mfma_f32_16x16x32_bf16(af[i], bfr[j], acc[i][j], 0, 0, 0);
    }
    __syncthreads();
  }
#pragma unroll
  for (int i = 0; i < IB; ++i)
#pragma unroll
    for (int r = 0; r < 4; ++r) {
      int m = m0 + wm + i * 16 + quad * 4 + r;
      if (OUT_BF16) {
        ushort* C = (ushort*)Cv;
#pragma unroll
        for (int j = 0; j < JB; ++j)
          C[(size_t)m * N + n0 + wn + j * 16 + col] = f2bf(acc[i][j][r]);
      } else {
        float* C = (float*)Cv;
#pragma unroll
        for (int j = 0; j < JB; ++j)
          C[(size_t)m * N + n0 + wn + j * 16 + col] = acc[i][j][r];
      }
    }
}

// ---------------- RoPE + layout ---------------------------------------------
__global__ __launch_bounds__(256) void rope_layout(
    const ushort* __restrict__ qkv, const float* __restrict__ fc,
    const float* __restrict__ fs, ushort* __restrict__ qb,
    ushort* __restrict__ kb, ushort* __restrict__ vt) {
  __shared__ ushort T[64][72];
  const int hh = blockIdx.x;
  const int s0 = blockIdx.y * 256;
  const int t = threadIdx.x;
  if (hh < 32) {
    ushort* dst = qb + (size_t)hh * S_LEN * 64;
    const float qs = 0.18033688011112042f;  // (1/8)*log2(e)
    const int sr = t >> 4, dc = (t & 15) * 4, i0 = (t & 15) * 2;
#pragma unroll 4
    for (int pass = 0; pass < 16; ++pass) {
      int s = s0 + pass * 16 + sr;
      ushort4 vv = *(const ushort4*)&qkv[(size_t)s * QKVF + hh * 64 + dc];
      float2 cc = *(const float2*)&fc[s * 32 + i0];
      float2 ss = *(const float2*)&fs[s * 32 + i0];
      float xr0 = bf2f(vv.x), xi0 = bf2f(vv.y), xr1 = bf2f(vv.z), xi1 = bf2f(vv.w);
      ushort4 ov;
      ov.x = f2bf((xr0 * cc.x - xi0 * ss.x) * qs); ov.y = f2bf((xr0 * ss.x + xi0 * cc.x) * qs);
      ov.z = f2bf((xr1 * cc.y - xi1 * ss.y) * qs); ov.w = f2bf((xr1 * ss.y + xi1 * cc.y) * qs);
      *(ushort4*)&dst[(size_t)s * 64 + dc] = ov;
    }
  } else if (hh < 40) {
    const int kh2 = hh - 32;
    const int sr8 = t >> 3;
    const int ch = t & 7;
#pragma unroll 2
    for (int pass = 0; pass < 8; ++pass) {
      int s = s0 + pass * 32 + sr8;
      ushort in[8], out[8];
      *(int4*)&in[0] = *(const int4*)&qkv[(size_t)s * QKVF + 2048 + kh2 * 64 + ch * 8];
      float4 cc = *(const float4*)&fc[s * 32 + ch * 4];
      float4 ss4 = *(const float4*)&fs[s * 32 + ch * 4];
      const float* cp = &cc.x; const float* sp = &ss4.x;
#pragma unroll
      for (int i = 0; i < 4; ++i) {
        float xr = bf2f(in[2 * i]), xi = bf2f(in[2 * i + 1]);
        out[2 * i]     = f2bf(xr * cp[i] - xi * sp[i]);
        out[2 * i + 1] = f2bf(xr * sp[i] + xi * cp[i]);
      }
      int r = s & 63, tile = s >> 6;
      // fragment order: p = (ch>>2)*4 + (r>>4), lane = (ch&3)*16 + (r&15)
      size_t pos = ((size_t)(kh2 * 32 + tile)) * 4096 +
                   ((size_t)(((ch >> 2) * 4 + (r >> 4)) * 64 + (ch & 3) * 16 + (r & 15))) * 8;
      *(int4*)&kb[pos] = *(const int4*)&out[0];
    }
  } else {
    const int vh = hh - 40;
    for (int sub = 0; sub < 4; ++sub) {
      int sb = s0 + sub * 64;
      int sr = t >> 2, dc = (t & 3) * 16;
      ushort tmp[16];
      *(int4*)&tmp[0] = *(const int4*)&qkv[(size_t)(sb + sr) * QKVF + 2560 + vh * 64 + dc];
      *(int4*)&tmp[8] = *(const int4*)&qkv[(size_t)(sb + sr) * QKVF + 2560 + vh * 64 + dc + 8];
      __syncthreads();
      const int pcol = ((sr & 15) << 2) | (sr >> 4);  // sigma: key sr -> position
#pragma unroll
      for (int k = 0; k < 16; ++k) T[dc + k][pcol] = tmp[k];
      __syncthreads();
      int d = t >> 2;
      int ch0 = (t & 3) * 2, ch1 = ch0 + 1;
      int tile = sb >> 6;
      size_t base = ((size_t)(vh * 32 + tile)) * 4096;
      // fragment order: p = (ch>>2)*4 + (d>>4), lane = (ch&3)*16 + (d&15)
      size_t p0 = base + ((size_t)(((ch0 >> 2) * 4 + (d >> 4)) * 64 + (ch0 & 3) * 16 + (d & 15))) * 8;
      size_t p1 = base + ((size_t)(((ch1 >> 2) * 4 + (d >> 4)) * 64 + (ch1 & 3) * 16 + (d & 15))) * 8;
      *(int4*)&vt[p0] = *(const int4*)&T[d][ch0 * 8];
      *(int4*)&vt[p1] = *(const int4*)&T[d][ch1 * 8];
    }
  }
}

// ---------------- Flash attention v12: pairs + khalf split, 4 waves/SIMD ----
// Grid (8 kvh, 64 pairs, 2 khalf) = 1024 blocks = 4/CU = 16 waves/CU.
// Block (kvh,y,kh): strips {y,127-y}, tiles t%2==kh only -> every wave does
// 16.5-17 tile-units (balanced by construction). Partial o (f32) and l go
// to obuf/lbuf; merge_norm adds the halves and normalizes (exp2-softmax is
// linear in keys). Barrier-free; per-wave Ps in LDS.
__global__ __launch_bounds__(256, 4) void attn(
    const ushort* __restrict__ qbg, const ushort* __restrict__ kbg,
    const ushort* __restrict__ vtg, float* __restrict__ obuf,
    float* __restrict__ lbuf) {
  __shared__ __align__(16) ushort Ps[4][2][16][64];  // [wave][strip][row][swz]
  const int kvh = blockIdx.x;
  const int y = blockIdx.y;
  const int khalf = blockIdx.z;
  const int sA = y, sB = 127 - y;
  const int ntA = (sA >> 2) + 1;
  const int ntB = (sB >> 2) + 1;
  const int wave = threadIdx.x >> 6;
  const int lane = threadIdx.x & 63;
  const int col = lane & 15, quad = lane >> 4;
  const int h = kvh * 4 + wave;
  const ushort* qh = qbg + (size_t)h * S_LEN * HD;
  const ushort* kbase = kbg + (size_t)kvh * 32 * 4096;
  const ushort* vbase = vtg + (size_t)kvh * 32 * 4096;
  float* obase = obuf + ((size_t)(khalf * 32 + h)) * S_LEN * HD;
  float* lbase = lbuf + ((size_t)(khalf * 32 + h)) * S_LEN;

  const int q0A = sA * 16, q0B = sB * 16;
  bf16x8 qfA[2], qfB[2];
  qfA[0] = *(const bf16x8*)&qh[(size_t)(q0A + col) * HD + quad * 8];
  qfA[1] = *(const bf16x8*)&qh[(size_t)(q0A + col) * HD + 32 + quad * 8];
  qfB[0] = *(const bf16x8*)&qh[(size_t)(q0B + col) * HD + quad * 8];
  qfB[1] = *(const bf16x8*)&qh[(size_t)(q0B + col) * HD + 32 + quad * 8];
  float lA[4] = {}, lB[4] = {};
  f32x4 oA[4] = {}, oB[4] = {};

  bf16x8 k0[8], v0[8], k1[8], v1[8];

  auto loadK = [&](bf16x8 (&kf)[8], int t) {
    const ushort* kt = kbase + (size_t)t * 4096;
#pragma unroll
    for (int p = 0; p < 8; ++p) kf[p] = *(const bf16x8*)&kt[(p * 64 + lane) * 8];
  };
  auto loadV = [&](bf16x8 (&vf)[8], int t) {
    const ushort* vtt = vbase + (size_t)t * 4096;
#pragma unroll
    for (int p = 0; p < 8; ++p) vf[p] = *(const bf16x8*)&vtt[(p * 64 + lane) * 8];
  };

  auto body = [&](bf16x8 (&kfc)[8], bf16x8 (&vfc)[8],
                  bf16x8 (&kfn)[8], bf16x8 (&vfn)[8], int t) {
    const bool doA = (t < ntA);
    const bool maskA = (t == ntA - 1);
    const bool maskB = (t == ntB - 1);
    const bool pre = (t + 2 < ntB);
    if (pre) loadK(kfn, t + 2);
    f32x4 scA[4] = {}, scB[4] = {};
#pragma unroll
    for (int c = 0; c < 2; ++c)
#pragma unroll
      for (int j = 0; j < 4; ++j)
        scB[j] = __builtin_amdgcn_mfma_f32_16x16x32_bf16(qfB[c], kfc[c * 4 + j], scB[j], 0, 0, 0);
    if (doA) {
#pragma unroll
      for (int c = 0; c < 2; ++c)
#pragma unroll
        for (int j = 0; j < 4; ++j)
          scA[j] = __builtin_amdgcn_mfma_f32_16x16x32_bf16(qfA[c], kfc[c * 4 + j], scA[j], 0, 0, 0);
    }
#pragma unroll
    for (int r = 0; r < 4; ++r) {
      const int prow = quad * 4 + r;
      const int psw = (((col >> 1) ^ (prow & 7)) << 3) + ((col & 1) << 2);
      const int rowq = q0B + prow;
      float pr[4];
#pragma unroll
      for (int j = 0; j < 4; ++j) {
        float e = __builtin_amdgcn_exp2f(scB[j][r]);
        if (maskB) e = (t * 64 + j * 16 + col > rowq) ? 0.f : e;
        pr[j] = e;
      }
      lB[r] += (pr[0] + pr[1]) + (pr[2] + pr[3]);
      uint2 pk;
      pk.x = pack_bf2_rz(pr[0], pr[1]);
      pk.y = pack_bf2_rz(pr[2], pr[3]);
      *(uint2*)&Ps[wave][1][prow][psw] = pk;
    }
    if (doA) {
#pragma unroll
      for (int r = 0; r < 4; ++r) {
        const int prow = quad * 4 + r;
        const int psw = (((col >> 1) ^ (prow & 7)) << 3) + ((col & 1) << 2);
        const int rowq = q0A + prow;
        float pr[4];
#pragma unroll
        for (int j = 0; j < 4; ++j) {
          float e = __builtin_amdgcn_exp2f(scA[j][r]);
          if (maskA) e = (t * 64 + j * 16 + col > rowq) ? 0.f : e;
          pr[j] = e;
        }
        lA[r] += (pr[0] + pr[1]) + (pr[2] + pr[3]);
        uint2 pk;
        pk.x = pack_bf2_rz(pr[0], pr[1]);
        pk.y = pack_bf2_rz(pr[2], pr[3]);
        *(uint2*)&Ps[wave][0][prow][psw] = pk;
      }
    }
    if (pre) loadV(vfn, t + 2);
#pragma unroll
    for (int c = 0; c < 2; ++c) {
      const int psr = ((c * 4 + quad) ^ (col & 7)) * 8;
      bf16x8 pfB = *(const bf16x8*)&Ps[wave][1][col][psr];
#pragma unroll
      for (int db = 0; db < 4; ++db)
        oB[db] = __builtin_amdgcn_mfma_f32_16x16x32_bf16(pfB, vfc[c * 4 + db], oB[db], 0, 0, 0);
    }
    if (doA) {
#pragma unroll
      for (int c = 0; c < 2; ++c) {
        const int psr = ((c * 4 + quad) ^ (col & 7)) * 8;
        bf16x8 pfA = *(const bf16x8*)&Ps[wave][0][col][psr];
#pragma unroll
        for (int db = 0; db < 4; ++db)
          oA[db] = __builtin_amdgcn_mfma_f32_16x16x32_bf16(pfA, vfc[c * 4 + db], oA[db], 0, 0, 0);
      }
    }
  };

  {
    int t = khalf;
    loadK(k0, t);
    loadV(v0, t);
    for (;;) {
      body(k0, v0, k1, v1, t);
      t += 2;
      if (t >= ntB) break;
      body(k1, v1, k0, v0, t);
      t += 2;
      if (t >= ntB) break;
    }
  }

  auto write_part = [&](const f32x4 (&o)[4], const float (&l)[4], int q0) {
#pragma unroll
    for (int r = 0; r < 4; ++r) {
      const int rowq = q0 + quad * 4 + r;
#pragma unroll
      for (int db = 0; db < 4; ++db)
        obase[(size_t)rowq * HD + db * 16 + col] = o[db][r];
      float ls = l[r];
      ls += __shfl_xor(ls, 1);
      ls += __shfl_xor(ls, 2);
      ls += __shfl_xor(ls, 4);
      ls += __shfl_xor(ls, 8);
      if (col == 0) lbase[rowq] = ls;
    }
  };
  write_part(oA, lA, q0A);
  write_part(oB, lB, q0B);
}

// ---------------- merge partials + normalize -> yb bf16 ---------------------
__global__ __launch_bounds__(256) void merge_norm(
    const float* __restrict__ obuf, const float* __restrict__ lbuf,
    ushort* __restrict__ yb) {
  const size_t OKH = (size_t)32 * S_LEN * HD;   // khalf stride in obuf
  const size_t LKH = (size_t)32 * S_LEN;        // khalf stride in lbuf
  int idx = blockIdx.x * 256 + threadIdx.x;     // 1M threads
  int dg = idx & 15;
  int row = (idx >> 4) & (S_LEN - 1);
  int h = idx >> 15;
  const float* o0 = obuf + ((size_t)h * S_LEN + row) * HD + dg * 4;
  const float* o1 = o0 + OKH;
  float4 a = *(const float4*)o0;
  float4 b = *(const float4*)o1;
  float l = lbuf[(size_t)h * S_LEN + row] + lbuf[LKH + (size_t)h * S_LEN + row];
  float inv = 1.0f / l;
  ushort4 o;
  o.x = f2bf((a.x + b.x) * inv);
  o.y = f2bf((a.y + b.y) * inv);
  o.z = f2bf((a.z + b.z) * inv);
  o.w = f2bf((a.w + b.w) * inv);
  *(ushort4*)&yb[(size_t)row * (NH * HD) + h * HD + dg * 4] = o;
}

extern "C" void kernel_launch(void* const* d_in, const int* in_sizes, int n_in,
                              void* d_out, int out_size, void* d_ws, size_t ws_size,
                              hipStream_t stream) {
  (void)in_sizes; (void)n_in; (void)out_size; (void)ws_size;
  const float* x  = (const float*)d_in[0];
  const float* fc = (const float*)d_in[1];
  const float* fs = (const float*)d_in[2];
  const float* wq = (const float*)d_in[4];
  const float* wk = (const float*)d_in[5];
  const float* wv = (const float*)d_in[6];
  const float* wo = (const float*)d_in[7];
  ushort* w = (ushort*)d_ws;
  const size_t M1 = 1024 * 1024;
  ushort* xb    = w;
  ushort* wqkvb = w + 4 * M1;
  ushort* wob   = w + 10 * M1;
  ushort* qkvb  = w + 14 * M1;
  ushort* qb    = w + 20 * M1;
  ushort* kb    = w + 24 * M1;
  ushort* vt    = w + 25 * M1;
  ushort* yb    = w + 26 * M1;
  float*  obuf  = (float*)(w + 30 * M1);                    // 2*32*2048*64 f32 = 33.5 MB
  float*  lbuf  = obuf + (size_t)2 * 32 * S_LEN * HD;       // 2*32*2048 f32 = 512 KB

  convert_all<<<14336, 256, 0, stream>>>(x, wq, wk, wv, wo, xb, wqkvb, wob);
  gemm_bt<1, 128, 96><<<dim3(QKVF / 96, S_LEN / 128), 256, 0, stream>>>(xb, wqkvb, qkvb, S_LEN, QKVF, DIMN);
  rope_layout<<<dim3(48, 8), 256, 0, stream>>>(qkvb, fc, fs, qb, kb, vt);
  attn<<<dim3(NKV, 64, 2), 256, 0, stream>>>(qb, kb, vt, obuf, lbuf);
  merge_norm<<<4096, 256, 0, stream>>>(obuf, lbuf, yb);
  gemm_bt<0, 64, 128><<<dim3(DIMN / 128, S_LEN / 64), 256, 0, stream>>>(yb, wob, d_out, S_LEN, DIMN, NH * HD);
}

// Round 5
// 254.401 us; speedup vs baseline: 1.9441x; 1.9441x over previous
//
#include <hip/hip_runtime.h>

// Fused attention prefill, bf16 MFMA pipeline.
// ws layout (ushort units, 1M = 1024*1024):
//   xb 0..4M | wqkvb 4M..10M | wob 10M..14M | qkvb 14M..20M | qb 20M..24M
//   kb 24M..25M | vt 25M..26M | yb 26M..30M   => 60 MB total.
// kb/vt layout: MFMA-fragment order. Per 64x64 tile:
//   addr = tile_base + (p*64 + lane)*8 ushorts, p = c*4 + j (j = B-operand
//   16-row group, c = K-chunk of 32), lane = quad*16 + col. A wave's
//   bf16x8 fragment load for (c,j) is one fully-coalesced 1 KB read.
// vt columns are sigma-permuted key positions: pos p holds key
//   u = (p&3)*16 + (p>>2), matching attn's P store order.
// attn v13: paired strips {y,127-y} (shared K/V loads, Sum nt = 33..34
// balanced) + khalf tile-parity split across the block's TWO waves ->
// 2048 blocks x 128 thr = 16 waves/CU = 4/SIMD (v9-v11 sat at 2/SIMD,
// latency-bound ~40us). No prefetch arrays (VGPR <= 128, no spill - the
// v12 failure). Barrier-free main loop; in-block LDS merge of khalf
// partials (exp2-sum softmax is linear in keys) + one final syncthreads.

typedef __attribute__((ext_vector_type(8))) __bf16 bf16x8;
typedef __attribute__((ext_vector_type(4))) float f32x4;

#define S_LEN 2048
#define DIMN  2048
#define NH    32
#define NKV   8
#define HD    64
#define QKVF  3072

struct DoPair { static constexpr bool value = true; };
struct OnlyB  { static constexpr bool value = false; };

__device__ __forceinline__ ushort f2bf(float f) {
  union { float f; unsigned u; } v; v.f = f;
  unsigned r = v.u + 0x7fffu + ((v.u >> 16) & 1u);
  return (ushort)(r >> 16);
}
__device__ __forceinline__ unsigned pack_bf2_rz(float a, float b) {
  union { float f; unsigned u; } va, vb; va.f = a; vb.f = b;
  return (va.u >> 16) | (vb.u & 0xffff0000u);
}
__device__ __forceinline__ float bf2f(ushort u) {
  union { unsigned u; float f; } v; v.u = ((unsigned)u) << 16;
  return v.f;
}
__device__ __forceinline__ void gld_lds16(const void* g, void* l) {
  __builtin_amdgcn_global_load_lds(
      (const __attribute__((address_space(1))) unsigned int*)g,
      (__attribute__((address_space(3))) unsigned int*)l, 16, 0, 0);
}

// ---------------- f32 -> bf16 conversion (x, [wq;wk;wv], wo) ----------------
__global__ __launch_bounds__(256) void convert_all(
    const float* __restrict__ x, const float* __restrict__ wq,
    const float* __restrict__ wk, const float* __restrict__ wv,
    const float* __restrict__ wo, ushort* __restrict__ xb,
    ushort* __restrict__ wqkvb, ushort* __restrict__ wob) {
  const size_t NX = 4u * 1024 * 1024;
  const size_t NK = 1024 * 1024;
  size_t idx = ((size_t)blockIdx.x * 256 + threadIdx.x) * 4;
  const float* src; ushort* dst;
  if (idx < NX)                { src = x  + idx;                  dst = xb + idx; }
  else if (idx < 2 * NX)       { src = wq + (idx - NX);           dst = wqkvb + (idx - NX); }
  else if (idx < 2 * NX + NK)  { src = wk + (idx - 2 * NX);       dst = wqkvb + NX + (idx - 2 * NX); }
  else if (idx < 2 * NX + 2*NK){ src = wv + (idx - 2 * NX - NK);  dst = wqkvb + NX + NK + (idx - 2 * NX - NK); }
  else                         { src = wo + (idx - 2 * NX - 2*NK);dst = wob + (idx - 2 * NX - 2 * NK); }
  float4 v = *(const float4*)src;
  ushort4 o; o.x = f2bf(v.x); o.y = f2bf(v.y); o.z = f2bf(v.z); o.w = f2bf(v.w);
  *(ushort4*)dst = o;
}

// ---------------- GEMM: dbuf LDS + XOR bank swizzle, tile (BM x BN) ---------
// Balanced grids: 512 blocks = exactly 2/CU, dbuf LDS < 64 KB (2-block
// residency). qkv: 128x96 (56 KB). wo: 64x128 (48 KB).
template <int OUT_BF16, int BM, int BN>
__global__ __launch_bounds__(256) void gemm_bt(
    const ushort* __restrict__ A, const ushort* __restrict__ B,
    void* __restrict__ Cv, int M, int N, int K) {
  constexpr int IB = BM / 32;
  constexpr int JB = BN / 32;
  constexpr int NGA = BM / 8;
  constexpr int GPW = (BM + BN) / 32;
  __shared__ __align__(16) ushort As[2][BM * 64];
  __shared__ __align__(16) ushort Bs[2][BN * 64];
  const int n0 = blockIdx.x * BN, m0 = blockIdx.y * BM;
  const int t = threadIdx.x;
  const int lane = t & 63, wave = t >> 6;
  const int wm = (wave >> 1) * (BM / 2), wn = (wave & 1) * (BN / 2);
  const int col = lane & 15, quad = lane >> 4;
  const int sw = col & 7;
  const int lrow = lane >> 3;
  const int scol = ((lane & 7) ^ lrow) * 8;
  f32x4 acc[IB][JB] = {};

  auto stage = [&](int b, int kk) {
#pragma unroll
    for (int c = 0; c < GPW; ++c) {
      int g = wave * GPW + c;
      if (g < NGA)
        gld_lds16(&A[(size_t)(m0 + g * 8 + lrow) * K + kk + scol], &As[b][g * 8 * 64]);
      else
        gld_lds16(&B[(size_t)(n0 + (g - NGA) * 8 + lrow) * K + kk + scol],
                  &Bs[b][(g - NGA) * 8 * 64]);
    }
  };

  stage(0, 0);
  __syncthreads();
  for (int kk = 0; kk < K; kk += 64) {
    const int b = (kk >> 6) & 1;
    if (kk + 64 < K) stage(b ^ 1, kk + 64);
#pragma unroll
    for (int c = 0; c < 2; ++c) {
      const int chs = ((c * 4 + quad) ^ sw) * 8;
      bf16x8 af[IB], bfr[JB];
#pragma unroll
      for (int i = 0; i < IB; ++i)
        af[i] = *(const bf16x8*)&As[b][(wm + i * 16 + col) * 64 + chs];
#pragma unroll
      for (int j = 0; j < JB; ++j)
        bfr[j] = *(const bf16x8*)&Bs[b][(wn + j * 16 + col) * 64 + chs];
#pragma unroll
      for (int i = 0; i < IB; ++i)
#pragma unroll
        for (int j = 0; j < JB; ++j)
          acc[i][j] = __builtin_amdgcn_mfma_f32_16x16x32_bf16(af[i], bfr[j], acc[i][j], 0, 0, 0);
    }
    __syncthreads();
  }
#pragma unroll
  for (int i = 0; i < IB; ++i)
#pragma unroll
    for (int r = 0; r < 4; ++r) {
      int m = m0 + wm + i * 16 + quad * 4 + r;
      if (OUT_BF16) {
        ushort* C = (ushort*)Cv;
#pragma unroll
        for (int j = 0; j < JB; ++j)
          C[(size_t)m * N + n0 + wn + j * 16 + col] = f2bf(acc[i][j][r]);
      } else {
        float* C = (float*)Cv;
#pragma unroll
        for (int j = 0; j < JB; ++j)
          C[(size_t)m * N + n0 + wn + j * 16 + col] = acc[i][j][r];
      }
    }
}

// ---------------- RoPE + layout ---------------------------------------------
__global__ __launch_bounds__(256) void rope_layout(
    const ushort* __restrict__ qkv, const float* __restrict__ fc,
    const float* __restrict__ fs, ushort* __restrict__ qb,
    ushort* __restrict__ kb, ushort* __restrict__ vt) {
  __shared__ ushort T[64][72];
  const int hh = blockIdx.x;
  const int s0 = blockIdx.y * 256;
  const int t = threadIdx.x;
  if (hh < 32) {
    ushort* dst = qb + (size_t)hh * S_LEN * 64;
    const float qs = 0.18033688011112042f;  // (1/8)*log2(e)
    const int sr = t >> 4, dc = (t & 15) * 4, i0 = (t & 15) * 2;
#pragma unroll 4
    for (int pass = 0; pass < 16; ++pass) {
      int s = s0 + pass * 16 + sr;
      ushort4 vv = *(const ushort4*)&qkv[(size_t)s * QKVF + hh * 64 + dc];
      float2 cc = *(const float2*)&fc[s * 32 + i0];
      float2 ss = *(const float2*)&fs[s * 32 + i0];
      float xr0 = bf2f(vv.x), xi0 = bf2f(vv.y), xr1 = bf2f(vv.z), xi1 = bf2f(vv.w);
      ushort4 ov;
      ov.x = f2bf((xr0 * cc.x - xi0 * ss.x) * qs); ov.y = f2bf((xr0 * ss.x + xi0 * cc.x) * qs);
      ov.z = f2bf((xr1 * cc.y - xi1 * ss.y) * qs); ov.w = f2bf((xr1 * ss.y + xi1 * cc.y) * qs);
      *(ushort4*)&dst[(size_t)s * 64 + dc] = ov;
    }
  } else if (hh < 40) {
    const int kh2 = hh - 32;
    const int sr8 = t >> 3;
    const int ch = t & 7;
#pragma unroll 2
    for (int pass = 0; pass < 8; ++pass) {
      int s = s0 + pass * 32 + sr8;
      ushort in[8], out[8];
      *(int4*)&in[0] = *(const int4*)&qkv[(size_t)s * QKVF + 2048 + kh2 * 64 + ch * 8];
      float4 cc = *(const float4*)&fc[s * 32 + ch * 4];
      float4 ss4 = *(const float4*)&fs[s * 32 + ch * 4];
      const float* cp = &cc.x; const float* sp = &ss4.x;
#pragma unroll
      for (int i = 0; i < 4; ++i) {
        float xr = bf2f(in[2 * i]), xi = bf2f(in[2 * i + 1]);
        out[2 * i]     = f2bf(xr * cp[i] - xi * sp[i]);
        out[2 * i + 1] = f2bf(xr * sp[i] + xi * cp[i]);
      }
      int r = s & 63, tile = s >> 6;
      // fragment order: p = (ch>>2)*4 + (r>>4), lane = (ch&3)*16 + (r&15)
      size_t pos = ((size_t)(kh2 * 32 + tile)) * 4096 +
                   ((size_t)(((ch >> 2) * 4 + (r >> 4)) * 64 + (ch & 3) * 16 + (r & 15))) * 8;
      *(int4*)&kb[pos] = *(const int4*)&out[0];
    }
  } else {
    const int vh = hh - 40;
    for (int sub = 0; sub < 4; ++sub) {
      int sb = s0 + sub * 64;
      int sr = t >> 2, dc = (t & 3) * 16;
      ushort tmp[16];
      *(int4*)&tmp[0] = *(const int4*)&qkv[(size_t)(sb + sr) * QKVF + 2560 + vh * 64 + dc];
      *(int4*)&tmp[8] = *(const int4*)&qkv[(size_t)(sb + sr) * QKVF + 2560 + vh * 64 + dc + 8];
      __syncthreads();
      const int pcol = ((sr & 15) << 2) | (sr >> 4);  // sigma: key sr -> position
#pragma unroll
      for (int k = 0; k < 16; ++k) T[dc + k][pcol] = tmp[k];
      __syncthreads();
      int d = t >> 2;
      int ch0 = (t & 3) * 2, ch1 = ch0 + 1;
      int tile = sb >> 6;
      size_t base = ((size_t)(vh * 32 + tile)) * 4096;
      // fragment order: p = (ch>>2)*4 + (d>>4), lane = (ch&3)*16 + (d&15)
      size_t p0 = base + ((size_t)(((ch0 >> 2) * 4 + (d >> 4)) * 64 + (ch0 & 3) * 16 + (d & 15))) * 8;
      size_t p1 = base + ((size_t)(((ch1 >> 2) * 4 + (d >> 4)) * 64 + (ch1 & 3) * 16 + (d & 15))) * 8;
      *(int4*)&vt[p0] = *(const int4*)&T[d][ch0 * 8];
      *(int4*)&vt[p1] = *(const int4*)&T[d][ch1 * 8];
    }
  }
}

// ---------------- Flash attention v13: pairs + khalf, 2-wave blocks ---------
// Grid (32 h, 64 y) = 2048 blocks x 128 thr = 8 blocks/CU = 16 waves/CU
// = 4 waves/SIMD. Wave khalf does tiles t%2==khalf of strips {y,127-y};
// every wave = 16.5-17 tile-units. Direct fragment loads (no prefetch
// arrays -> no spill risk), barrier-free main loop, per-wave Ps; khalf
// partials merged in-block via LDS + one syncthreads at the end.
__global__ __launch_bounds__(128, 4) void attn(
    const ushort* __restrict__ qbg, const ushort* __restrict__ kbg,
    const ushort* __restrict__ vtg, ushort* __restrict__ yb) {
  __shared__ __align__(16) ushort Ps[2][2][16][64];  // [khalf][strip][row][swz]
  __shared__ __align__(16) float Mrg[2][64][20];     // [strip][lane][o16,l4]
  const int h = blockIdx.x;            // 0..31
  const int y = blockIdx.y;            // 0..63
  const int kvh = h >> 2;
  const int khalf = threadIdx.x >> 6;  // wave 0/1
  const int lane = threadIdx.x & 63;
  const int col = lane & 15, quad = lane >> 4;
  const int sA = y, sB = 127 - y;
  const int ntA = (sA >> 2) + 1;
  const int ntB = (sB >> 2) + 1;
  const ushort* qh = qbg + (size_t)h * S_LEN * HD;
  const ushort* kbase = kbg + (size_t)kvh * 32 * 4096;
  const ushort* vbase = vtg + (size_t)kvh * 32 * 4096;

  const int q0A = sA * 16, q0B = sB * 16;
  bf16x8 qfA[2], qfB[2];
  qfA[0] = *(const bf16x8*)&qh[(size_t)(q0A + col) * HD + quad * 8];
  qfA[1] = *(const bf16x8*)&qh[(size_t)(q0A + col) * HD + 32 + quad * 8];
  qfB[0] = *(const bf16x8*)&qh[(size_t)(q0B + col) * HD + quad * 8];
  qfB[1] = *(const bf16x8*)&qh[(size_t)(q0B + col) * HD + 32 + quad * 8];
  float lA[4] = {}, lB[4] = {};
  f32x4 oA[4] = {}, oB[4] = {};

  auto body = [&](int t, auto tag) {
    constexpr bool DOA = decltype(tag)::value;
    const ushort* kt  = kbase + (size_t)t * 4096;
    const ushort* vtt = vbase + (size_t)t * 4096;
    const bool maskA = (t == ntA - 1);
    const bool maskB = (t == ntB - 1);
    f32x4 scA[4] = {}, scB[4] = {};
#pragma unroll
    for (int c = 0; c < 2; ++c)
#pragma unroll
      for (int j = 0; j < 4; ++j) {
        bf16x8 kf = *(const bf16x8*)&kt[((c * 4 + j) * 64 + lane) * 8];
        scB[j] = __builtin_amdgcn_mfma_f32_16x16x32_bf16(qfB[c], kf, scB[j], 0, 0, 0);
        if constexpr (DOA)
          scA[j] = __builtin_amdgcn_mfma_f32_16x16x32_bf16(qfA[c], kf, scA[j], 0, 0, 0);
      }
#pragma unroll
    for (int r = 0; r < 4; ++r) {
      const int prow = quad * 4 + r;
      const int psw = (((col >> 1) ^ (prow & 7)) << 3) + ((col & 1) << 2);
      const int rowq = q0B + prow;
      float pr[4];
#pragma unroll
      for (int j = 0; j < 4; ++j) {
        float e = __builtin_amdgcn_exp2f(scB[j][r]);
        if (maskB) e = (t * 64 + j * 16 + col > rowq) ? 0.f : e;
        pr[j] = e;
      }
      lB[r] += (pr[0] + pr[1]) + (pr[2] + pr[3]);
      uint2 pk;
      pk.x = pack_bf2_rz(pr[0], pr[1]);
      pk.y = pack_bf2_rz(pr[2], pr[3]);
      *(uint2*)&Ps[khalf][1][prow][psw] = pk;
    }
    if constexpr (DOA) {
#pragma unroll
      for (int r = 0; r < 4; ++r) {
        const int prow = quad * 4 + r;
        const int psw = (((col >> 1) ^ (prow & 7)) << 3) + ((col & 1) << 2);
        const int rowq = q0A + prow;
        float pr[4];
#pragma unroll
        for (int j = 0; j < 4; ++j) {
          float e = __builtin_amdgcn_exp2f(scA[j][r]);
          if (maskA) e = (t * 64 + j * 16 + col > rowq) ? 0.f : e;
          pr[j] = e;
        }
        lA[r] += (pr[0] + pr[1]) + (pr[2] + pr[3]);
        uint2 pk;
        pk.x = pack_bf2_rz(pr[0], pr[1]);
        pk.y = pack_bf2_rz(pr[2], pr[3]);
        *(uint2*)&Ps[khalf][0][prow][psw] = pk;
      }
    }
#pragma unroll
    for (int c = 0; c < 2; ++c) {
      const int psr = ((c * 4 + quad) ^ (col & 7)) * 8;
      bf16x8 pfB = *(const bf16x8*)&Ps[khalf][1][col][psr];
      bf16x8 pfA;
      if constexpr (DOA) pfA = *(const bf16x8*)&Ps[khalf][0][col][psr];
#pragma unroll
      for (int db = 0; db < 4; ++db) {
        bf16x8 vf = *(const bf16x8*)&vtt[((c * 4 + db) * 64 + lane) * 8];
        oB[db] = __builtin_amdgcn_mfma_f32_16x16x32_bf16(pfB, vf, oB[db], 0, 0, 0);
        if constexpr (DOA)
          oA[db] = __builtin_amdgcn_mfma_f32_16x16x32_bf16(pfA, vf, oA[db], 0, 0, 0);
      }
    }
  };

  for (int t = khalf; t < ntB; t += 2) {
    if (t < ntA) body(t, DoPair{});
    else         body(t, OnlyB{});
  }

  // khalf=1 publishes partials; khalf=0 merges and writes.
  if (khalf == 1) {
#pragma unroll
    for (int db = 0; db < 4; ++db)
#pragma unroll
      for (int r = 0; r < 4; ++r) {
        Mrg[0][lane][db * 4 + r] = oA[db][r];
        Mrg[1][lane][db * 4 + r] = oB[db][r];
      }
#pragma unroll
    for (int r = 0; r < 4; ++r) {
      Mrg[0][lane][16 + r] = lA[r];
      Mrg[1][lane][16 + r] = lB[r];
    }
  }
  __syncthreads();
  if (khalf == 0) {
#pragma unroll
    for (int db = 0; db < 4; ++db)
#pragma unroll
      for (int r = 0; r < 4; ++r) {
        oA[db][r] += Mrg[0][lane][db * 4 + r];
        oB[db][r] += Mrg[1][lane][db * 4 + r];
      }
#pragma unroll
    for (int r = 0; r < 4; ++r) {
      lA[r] += Mrg[0][lane][16 + r];
      lB[r] += Mrg[1][lane][16 + r];
    }
    auto write_out = [&](const f32x4 (&o)[4], const float (&l)[4], int q0) {
#pragma unroll
      for (int r = 0; r < 4; ++r) {
        float ls = l[r];
        ls += __shfl_xor(ls, 1);
        ls += __shfl_xor(ls, 2);
        ls += __shfl_xor(ls, 4);
        ls += __shfl_xor(ls, 8);
        float inv = 1.0f / ls;
        int rowq = q0 + quad * 4 + r;
#pragma unroll
        for (int db = 0; db < 4; ++db)
          yb[(size_t)rowq * (NH * HD) + h * HD + db * 16 + col] = f2bf(o[db][r] * inv);
      }
    };
    write_out(oA, lA, q0A);
    write_out(oB, lB, q0B);
  }
}

extern "C" void kernel_launch(void* const* d_in, const int* in_sizes, int n_in,
                              void* d_out, int out_size, void* d_ws, size_t ws_size,
                              hipStream_t stream) {
  (void)in_sizes; (void)n_in; (void)out_size; (void)ws_size;
  const float* x  = (const float*)d_in[0];
  const float* fc = (const float*)d_in[1];
  const float* fs = (const float*)d_in[2];
  const float* wq = (const float*)d_in[4];
  const float* wk = (const float*)d_in[5];
  const float* wv = (const float*)d_in[6];
  const float* wo = (const float*)d_in[7];
  ushort* w = (ushort*)d_ws;
  const size_t M1 = 1024 * 1024;
  ushort* xb    = w;
  ushort* wqkvb = w + 4 * M1;
  ushort* wob   = w + 10 * M1;
  ushort* qkvb  = w + 14 * M1;
  ushort* qb    = w + 20 * M1;
  ushort* kb    = w + 24 * M1;
  ushort* vt    = w + 25 * M1;
  ushort* yb    = w + 26 * M1;

  convert_all<<<14336, 256, 0, stream>>>(x, wq, wk, wv, wo, xb, wqkvb, wob);
  gemm_bt<1, 128, 96><<<dim3(QKVF / 96, S_LEN / 128), 256, 0, stream>>>(xb, wqkvb, qkvb, S_LEN, QKVF, DIMN);
  rope_layout<<<dim3(48, 8), 256, 0, stream>>>(qkvb, fc, fs, qb, kb, vt);
  attn<<<dim3(32, 64), 128, 0, stream>>>(qb, kb, vt, yb);
  gemm_bt<0, 64, 128><<<dim3(DIMN / 128, S_LEN / 64), 256, 0, stream>>>(yb, wob, d_out, S_LEN, DIMN, NH * HD);
}

// Round 6
// 218.413 us; speedup vs baseline: 2.2645x; 1.1648x over previous
//
#include <hip/hip_runtime.h>

// Fused attention prefill, bf16 MFMA pipeline.
// ws layout (ushort units, 1M = 1024*1024):
//   xb 0..4M | wqkvb 4M..10M | wob 10M..14M | qkvb 14M..20M | qb 20M..24M
//   kb 24M..25M | vt 25M..26M | yb 26M..30M   => 60 MB total.
// kb/vt layout: MFMA-fragment order. Per 64x64 tile:
//   addr = tile_base + (p*64 + lane)*8 ushorts, p = c*4 + j (j = B-operand
//   16-row group, c = K-chunk of 32), lane = quad*16 + col. A wave's
//   bf16x8 fragment load for (c,j) is one fully-coalesced 1 KB read.
// vt columns are sigma-permuted key positions: pos p holds key
//   u = (p&3)*16 + (p>>2), matching attn's P store order.
// attn v14 = v13 structure with the register-allocator fix:
//   __launch_bounds__(128, 2). v12/v13 showed launch_bounds(.,4) makes
//   LLVM clamp to 64 VGPRs (chasing 8 waves/EU) and spill every tile
//   (VGPR=64, WRITE 2x, dur 2x). The body naturally needs ~124 VGPRs
//   (v11 measured) which already satisfies the <=128 cap for 4 waves/SIMD,
//   so the 2048-block x 2-wave grid reaches 16 waves/CU without forcing.

typedef __attribute__((ext_vector_type(8))) __bf16 bf16x8;
typedef __attribute__((ext_vector_type(4))) float f32x4;

#define S_LEN 2048
#define DIMN  2048
#define NH    32
#define NKV   8
#define HD    64
#define QKVF  3072

struct DoPair { static constexpr bool value = true; };
struct OnlyB  { static constexpr bool value = false; };

__device__ __forceinline__ ushort f2bf(float f) {
  union { float f; unsigned u; } v; v.f = f;
  unsigned r = v.u + 0x7fffu + ((v.u >> 16) & 1u);
  return (ushort)(r >> 16);
}
__device__ __forceinline__ unsigned pack_bf2_rz(float a, float b) {
  union { float f; unsigned u; } va, vb; va.f = a; vb.f = b;
  return (va.u >> 16) | (vb.u & 0xffff0000u);
}
__device__ __forceinline__ float bf2f(ushort u) {
  union { unsigned u; float f; } v; v.u = ((unsigned)u) << 16;
  return v.f;
}
__device__ __forceinline__ void gld_lds16(const void* g, void* l) {
  __builtin_amdgcn_global_load_lds(
      (const __attribute__((address_space(1))) unsigned int*)g,
      (__attribute__((address_space(3))) unsigned int*)l, 16, 0, 0);
}

// ---------------- f32 -> bf16 conversion (x, [wq;wk;wv], wo) ----------------
__global__ __launch_bounds__(256) void convert_all(
    const float* __restrict__ x, const float* __restrict__ wq,
    const float* __restrict__ wk, const float* __restrict__ wv,
    const float* __restrict__ wo, ushort* __restrict__ xb,
    ushort* __restrict__ wqkvb, ushort* __restrict__ wob) {
  const size_t NX = 4u * 1024 * 1024;
  const size_t NK = 1024 * 1024;
  size_t idx = ((size_t)blockIdx.x * 256 + threadIdx.x) * 4;
  const float* src; ushort* dst;
  if (idx < NX)                { src = x  + idx;                  dst = xb + idx; }
  else if (idx < 2 * NX)       { src = wq + (idx - NX);           dst = wqkvb + (idx - NX); }
  else if (idx < 2 * NX + NK)  { src = wk + (idx - 2 * NX);       dst = wqkvb + NX + (idx - 2 * NX); }
  else if (idx < 2 * NX + 2*NK){ src = wv + (idx - 2 * NX - NK);  dst = wqkvb + NX + NK + (idx - 2 * NX - NK); }
  else                         { src = wo + (idx - 2 * NX - 2*NK);dst = wob + (idx - 2 * NX - 2 * NK); }
  float4 v = *(const float4*)src;
  ushort4 o; o.x = f2bf(v.x); o.y = f2bf(v.y); o.z = f2bf(v.z); o.w = f2bf(v.w);
  *(ushort4*)dst = o;
}

// ---------------- GEMM: dbuf LDS + XOR bank swizzle, tile (BM x BN) ---------
// Balanced grids: 512 blocks = exactly 2/CU, dbuf LDS < 64 KB (2-block
// residency). qkv: 128x96 (56 KB). wo: 64x128 (48 KB).
template <int OUT_BF16, int BM, int BN>
__global__ __launch_bounds__(256) void gemm_bt(
    const ushort* __restrict__ A, const ushort* __restrict__ B,
    void* __restrict__ Cv, int M, int N, int K) {
  constexpr int IB = BM / 32;
  constexpr int JB = BN / 32;
  constexpr int NGA = BM / 8;
  constexpr int GPW = (BM + BN) / 32;
  __shared__ __align__(16) ushort As[2][BM * 64];
  __shared__ __align__(16) ushort Bs[2][BN * 64];
  const int n0 = blockIdx.x * BN, m0 = blockIdx.y * BM;
  const int t = threadIdx.x;
  const int lane = t & 63, wave = t >> 6;
  const int wm = (wave >> 1) * (BM / 2), wn = (wave & 1) * (BN / 2);
  const int col = lane & 15, quad = lane >> 4;
  const int sw = col & 7;
  const int lrow = lane >> 3;
  const int scol = ((lane & 7) ^ lrow) * 8;
  f32x4 acc[IB][JB] = {};

  auto stage = [&](int b, int kk) {
#pragma unroll
    for (int c = 0; c < GPW; ++c) {
      int g = wave * GPW + c;
      if (g < NGA)
        gld_lds16(&A[(size_t)(m0 + g * 8 + lrow) * K + kk + scol], &As[b][g * 8 * 64]);
      else
        gld_lds16(&B[(size_t)(n0 + (g - NGA) * 8 + lrow) * K + kk + scol],
                  &Bs[b][(g - NGA) * 8 * 64]);
    }
  };

  stage(0, 0);
  __syncthreads();
  for (int kk = 0; kk < K; kk += 64) {
    const int b = (kk >> 6) & 1;
    if (kk + 64 < K) stage(b ^ 1, kk + 64);
#pragma unroll
    for (int c = 0; c < 2; ++c) {
      const int chs = ((c * 4 + quad) ^ sw) * 8;
      bf16x8 af[IB], bfr[JB];
#pragma unroll
      for (int i = 0; i < IB; ++i)
        af[i] = *(const bf16x8*)&As[b][(wm + i * 16 + col) * 64 + chs];
#pragma unroll
      for (int j = 0; j < JB; ++j)
        bfr[j] = *(const bf16x8*)&Bs[b][(wn + j * 16 + col) * 64 + chs];
#pragma unroll
      for (int i = 0; i < IB; ++i)
#pragma unroll
        for (int j = 0; j < JB; ++j)
          acc[i][j] = __builtin_amdgcn_mfma_f32_16x16x32_bf16(af[i], bfr[j], acc[i][j], 0, 0, 0);
    }
    __syncthreads();
  }
#pragma unroll
  for (int i = 0; i < IB; ++i)
#pragma unroll
    for (int r = 0; r < 4; ++r) {
      int m = m0 + wm + i * 16 + quad * 4 + r;
      if (OUT_BF16) {
        ushort* C = (ushort*)Cv;
#pragma unroll
        for (int j = 0; j < JB; ++j)
          C[(size_t)m * N + n0 + wn + j * 16 + col] = f2bf(acc[i][j][r]);
      } else {
        float* C = (float*)Cv;
#pragma unroll
        for (int j = 0; j < JB; ++j)
          C[(size_t)m * N + n0 + wn + j * 16 + col] = acc[i][j][r];
      }
    }
}

// ---------------- RoPE + layout ---------------------------------------------
__global__ __launch_bounds__(256) void rope_layout(
    const ushort* __restrict__ qkv, const float* __restrict__ fc,
    const float* __restrict__ fs, ushort* __restrict__ qb,
    ushort* __restrict__ kb, ushort* __restrict__ vt) {
  __shared__ ushort T[64][72];
  const int hh = blockIdx.x;
  const int s0 = blockIdx.y * 256;
  const int t = threadIdx.x;
  if (hh < 32) {
    ushort* dst = qb + (size_t)hh * S_LEN * 64;
    const float qs = 0.18033688011112042f;  // (1/8)*log2(e)
    const int sr = t >> 4, dc = (t & 15) * 4, i0 = (t & 15) * 2;
#pragma unroll 4
    for (int pass = 0; pass < 16; ++pass) {
      int s = s0 + pass * 16 + sr;
      ushort4 vv = *(const ushort4*)&qkv[(size_t)s * QKVF + hh * 64 + dc];
      float2 cc = *(const float2*)&fc[s * 32 + i0];
      float2 ss = *(const float2*)&fs[s * 32 + i0];
      float xr0 = bf2f(vv.x), xi0 = bf2f(vv.y), xr1 = bf2f(vv.z), xi1 = bf2f(vv.w);
      ushort4 ov;
      ov.x = f2bf((xr0 * cc.x - xi0 * ss.x) * qs); ov.y = f2bf((xr0 * ss.x + xi0 * cc.x) * qs);
      ov.z = f2bf((xr1 * cc.y - xi1 * ss.y) * qs); ov.w = f2bf((xr1 * ss.y + xi1 * cc.y) * qs);
      *(ushort4*)&dst[(size_t)s * 64 + dc] = ov;
    }
  } else if (hh < 40) {
    const int kh2 = hh - 32;
    const int sr8 = t >> 3;
    const int ch = t & 7;
#pragma unroll 2
    for (int pass = 0; pass < 8; ++pass) {
      int s = s0 + pass * 32 + sr8;
      ushort in[8], out[8];
      *(int4*)&in[0] = *(const int4*)&qkv[(size_t)s * QKVF + 2048 + kh2 * 64 + ch * 8];
      float4 cc = *(const float4*)&fc[s * 32 + ch * 4];
      float4 ss4 = *(const float4*)&fs[s * 32 + ch * 4];
      const float* cp = &cc.x; const float* sp = &ss4.x;
#pragma unroll
      for (int i = 0; i < 4; ++i) {
        float xr = bf2f(in[2 * i]), xi = bf2f(in[2 * i + 1]);
        out[2 * i]     = f2bf(xr * cp[i] - xi * sp[i]);
        out[2 * i + 1] = f2bf(xr * sp[i] + xi * cp[i]);
      }
      int r = s & 63, tile = s >> 6;
      // fragment order: p = (ch>>2)*4 + (r>>4), lane = (ch&3)*16 + (r&15)
      size_t pos = ((size_t)(kh2 * 32 + tile)) * 4096 +
                   ((size_t)(((ch >> 2) * 4 + (r >> 4)) * 64 + (ch & 3) * 16 + (r & 15))) * 8;
      *(int4*)&kb[pos] = *(const int4*)&out[0];
    }
  } else {
    const int vh = hh - 40;
    for (int sub = 0; sub < 4; ++sub) {
      int sb = s0 + sub * 64;
      int sr = t >> 2, dc = (t & 3) * 16;
      ushort tmp[16];
      *(int4*)&tmp[0] = *(const int4*)&qkv[(size_t)(sb + sr) * QKVF + 2560 + vh * 64 + dc];
      *(int4*)&tmp[8] = *(const int4*)&qkv[(size_t)(sb + sr) * QKVF + 2560 + vh * 64 + dc + 8];
      __syncthreads();
      const int pcol = ((sr & 15) << 2) | (sr >> 4);  // sigma: key sr -> position
#pragma unroll
      for (int k = 0; k < 16; ++k) T[dc + k][pcol] = tmp[k];
      __syncthreads();
      int d = t >> 2;
      int ch0 = (t & 3) * 2, ch1 = ch0 + 1;
      int tile = sb >> 6;
      size_t base = ((size_t)(vh * 32 + tile)) * 4096;
      // fragment order: p = (ch>>2)*4 + (d>>4), lane = (ch&3)*16 + (d&15)
      size_t p0 = base + ((size_t)(((ch0 >> 2) * 4 + (d >> 4)) * 64 + (ch0 & 3) * 16 + (d & 15))) * 8;
      size_t p1 = base + ((size_t)(((ch1 >> 2) * 4 + (d >> 4)) * 64 + (ch1 & 3) * 16 + (d & 15))) * 8;
      *(int4*)&vt[p0] = *(const int4*)&T[d][ch0 * 8];
      *(int4*)&vt[p1] = *(const int4*)&T[d][ch1 * 8];
    }
  }
}

// ---------------- Flash attention v14: pairs + khalf, 2-wave blocks ---------
// Grid (32 h, 64 y) = 2048 blocks x 128 thr -> up to 8 blocks/CU = 16
// waves/CU = 4 waves/SIMD (needs VGPR <= 128; natural allocation ~124).
// Wave khalf does tiles t%2==khalf of strips {y,127-y}; every wave =
// 16.5-17 tile-units (balanced by construction). Direct fragment loads,
// barrier-free main loop, per-wave Ps; khalf partials merged in-block via
// LDS + one syncthreads. launch_bounds(128,2): do NOT request 4 waves/EU
// (v12/v13: that clamps the allocator to 64 VGPR -> spills -> 2x slower).
__global__ __launch_bounds__(128, 2) void attn(
    const ushort* __restrict__ qbg, const ushort* __restrict__ kbg,
    const ushort* __restrict__ vtg, ushort* __restrict__ yb) {
  __shared__ __align__(16) ushort Ps[2][2][16][64];  // [khalf][strip][row][swz]
  __shared__ __align__(16) float Mrg[2][64][20];     // [strip][lane][o16,l4]
  const int h = blockIdx.x;            // 0..31
  const int y = blockIdx.y;            // 0..63
  const int kvh = h >> 2;
  const int khalf = threadIdx.x >> 6;  // wave 0/1
  const int lane = threadIdx.x & 63;
  const int col = lane & 15, quad = lane >> 4;
  const int sA = y, sB = 127 - y;
  const int ntA = (sA >> 2) + 1;
  const int ntB = (sB >> 2) + 1;
  const ushort* qh = qbg + (size_t)h * S_LEN * HD;
  const ushort* kbase = kbg + (size_t)kvh * 32 * 4096;
  const ushort* vbase = vtg + (size_t)kvh * 32 * 4096;

  const int q0A = sA * 16, q0B = sB * 16;
  bf16x8 qfA[2], qfB[2];
  qfA[0] = *(const bf16x8*)&qh[(size_t)(q0A + col) * HD + quad * 8];
  qfA[1] = *(const bf16x8*)&qh[(size_t)(q0A + col) * HD + 32 + quad * 8];
  qfB[0] = *(const bf16x8*)&qh[(size_t)(q0B + col) * HD + quad * 8];
  qfB[1] = *(const bf16x8*)&qh[(size_t)(q0B + col) * HD + 32 + quad * 8];
  float lA[4] = {}, lB[4] = {};
  f32x4 oA[4] = {}, oB[4] = {};

  auto body = [&](int t, auto tag) {
    constexpr bool DOA = decltype(tag)::value;
    const ushort* kt  = kbase + (size_t)t * 4096;
    const ushort* vtt = vbase + (size_t)t * 4096;
    const bool maskA = (t == ntA - 1);
    const bool maskB = (t == ntB - 1);
    f32x4 scA[4] = {}, scB[4] = {};
#pragma unroll
    for (int c = 0; c < 2; ++c)
#pragma unroll
      for (int j = 0; j < 4; ++j) {
        bf16x8 kf = *(const bf16x8*)&kt[((c * 4 + j) * 64 + lane) * 8];
        scB[j] = __builtin_amdgcn_mfma_f32_16x16x32_bf16(qfB[c], kf, scB[j], 0, 0, 0);
        if constexpr (DOA)
          scA[j] = __builtin_amdgcn_mfma_f32_16x16x32_bf16(qfA[c], kf, scA[j], 0, 0, 0);
      }
#pragma unroll
    for (int r = 0; r < 4; ++r) {
      const int prow = quad * 4 + r;
      const int psw = (((col >> 1) ^ (prow & 7)) << 3) + ((col & 1) << 2);
      const int rowq = q0B + prow;
      float pr[4];
#pragma unroll
      for (int j = 0; j < 4; ++j) {
        float e = __builtin_amdgcn_exp2f(scB[j][r]);
        if (maskB) e = (t * 64 + j * 16 + col > rowq) ? 0.f : e;
        pr[j] = e;
      }
      lB[r] += (pr[0] + pr[1]) + (pr[2] + pr[3]);
      uint2 pk;
      pk.x = pack_bf2_rz(pr[0], pr[1]);
      pk.y = pack_bf2_rz(pr[2], pr[3]);
      *(uint2*)&Ps[khalf][1][prow][psw] = pk;
    }
    if constexpr (DOA) {
#pragma unroll
      for (int r = 0; r < 4; ++r) {
        const int prow = quad * 4 + r;
        const int psw = (((col >> 1) ^ (prow & 7)) << 3) + ((col & 1) << 2);
        const int rowq = q0A + prow;
        float pr[4];
#pragma unroll
        for (int j = 0; j < 4; ++j) {
          float e = __builtin_amdgcn_exp2f(scA[j][r]);
          if (maskA) e = (t * 64 + j * 16 + col > rowq) ? 0.f : e;
          pr[j] = e;
        }
        lA[r] += (pr[0] + pr[1]) + (pr[2] + pr[3]);
        uint2 pk;
        pk.x = pack_bf2_rz(pr[0], pr[1]);
        pk.y = pack_bf2_rz(pr[2], pr[3]);
        *(uint2*)&Ps[khalf][0][prow][psw] = pk;
      }
    }
#pragma unroll
    for (int c = 0; c < 2; ++c) {
      const int psr = ((c * 4 + quad) ^ (col & 7)) * 8;
      bf16x8 pfB = *(const bf16x8*)&Ps[khalf][1][col][psr];
      bf16x8 pfA;
      if constexpr (DOA) pfA = *(const bf16x8*)&Ps[khalf][0][col][psr];
#pragma unroll
      for (int db = 0; db < 4; ++db) {
        bf16x8 vf = *(const bf16x8*)&vtt[((c * 4 + db) * 64 + lane) * 8];
        oB[db] = __builtin_amdgcn_mfma_f32_16x16x32_bf16(pfB, vf, oB[db], 0, 0, 0);
        if constexpr (DOA)
          oA[db] = __builtin_amdgcn_mfma_f32_16x16x32_bf16(pfA, vf, oA[db], 0, 0, 0);
      }
    }
  };

  for (int t = khalf; t < ntB; t += 2) {
    if (t < ntA) body(t, DoPair{});
    else         body(t, OnlyB{});
  }

  // khalf=1 publishes partials; khalf=0 merges and writes.
  if (khalf == 1) {
#pragma unroll
    for (int db = 0; db < 4; ++db)
#pragma unroll
      for (int r = 0; r < 4; ++r) {
        Mrg[0][lane][db * 4 + r] = oA[db][r];
        Mrg[1][lane][db * 4 + r] = oB[db][r];
      }
#pragma unroll
    for (int r = 0; r < 4; ++r) {
      Mrg[0][lane][16 + r] = lA[r];
      Mrg[1][lane][16 + r] = lB[r];
    }
  }
  __syncthreads();
  if (khalf == 0) {
#pragma unroll
    for (int db = 0; db < 4; ++db)
#pragma unroll
      for (int r = 0; r < 4; ++r) {
        oA[db][r] += Mrg[0][lane][db * 4 + r];
        oB[db][r] += Mrg[1][lane][db * 4 + r];
      }
#pragma unroll
    for (int r = 0; r < 4; ++r) {
      lA[r] += Mrg[0][lane][16 + r];
      lB[r] += Mrg[1][lane][16 + r];
    }
    auto write_out = [&](const f32x4 (&o)[4], const float (&l)[4], int q0) {
#pragma unroll
      for (int r = 0; r < 4; ++r) {
        float ls = l[r];
        ls += __shfl_xor(ls, 1);
        ls += __shfl_xor(ls, 2);
        ls += __shfl_xor(ls, 4);
        ls += __shfl_xor(ls, 8);
        float inv = 1.0f / ls;
        int rowq = q0 + quad * 4 + r;
#pragma unroll
        for (int db = 0; db < 4; ++db)
          yb[(size_t)rowq * (NH * HD) + h * HD + db * 16 + col] = f2bf(o[db][r] * inv);
      }
    };
    write_out(oA, lA, q0A);
    write_out(oB, lB, q0B);
  }
}

extern "C" void kernel_launch(void* const* d_in, const int* in_sizes, int n_in,
                              void* d_out, int out_size, void* d_ws, size_t ws_size,
                              hipStream_t stream) {
  (void)in_sizes; (void)n_in; (void)out_size; (void)ws_size;
  const float* x  = (const float*)d_in[0];
  const float* fc = (const float*)d_in[1];
  const float* fs = (const float*)d_in[2];
  const float* wq = (const float*)d_in[4];
  const float* wk = (const float*)d_in[5];
  const float* wv = (const float*)d_in[6];
  const float* wo = (const float*)d_in[7];
  ushort* w = (ushort*)d_ws;
  const size_t M1 = 1024 * 1024;
  ushort* xb    = w;
  ushort* wqkvb = w + 4 * M1;
  ushort* wob   = w + 10 * M1;
  ushort* qkvb  = w + 14 * M1;
  ushort* qb    = w + 20 * M1;
  ushort* kb    = w + 24 * M1;
  ushort* vt    = w + 25 * M1;
  ushort* yb    = w + 26 * M1;

  convert_all<<<14336, 256, 0, stream>>>(x, wq, wk, wv, wo, xb, wqkvb, wob);
  gemm_bt<1, 128, 96><<<dim3(QKVF / 96, S_LEN / 128), 256, 0, stream>>>(xb, wqkvb, qkvb, S_LEN, QKVF, DIMN);
  rope_layout<<<dim3(48, 8), 256, 0, stream>>>(qkvb, fc, fs, qb, kb, vt);
  attn<<<dim3(32, 64), 128, 0, stream>>>(qb, kb, vt, yb);
  gemm_bt<0, 64, 128><<<dim3(DIMN / 128, S_LEN / 64), 256, 0, stream>>>(yb, wob, d_out, S_LEN, DIMN, NH * HD);
}

// Round 7
// 212.813 us; speedup vs baseline: 2.3241x; 1.0263x over previous
//
#include <hip/hip_runtime.h>

// Fused attention prefill, bf16 MFMA pipeline.
// ws layout (ushort units, 1M = 1024*1024):
//   xb 0..4M | wqkvb 4M..10M | wob 10M..14M | qkvb 14M..20M | qb 20M..24M
//   kb 24M..25M | vt 25M..26M | yb 26M..30M   => 60 MB total.
// kb/vt layout: MFMA-fragment order. Per 64x64 tile:
//   addr = tile_base + (p*64 + lane)*8 ushorts, p = c*4 + j (j = B-operand
//   16-row group, c = K-chunk of 32), lane = quad*16 + col. A wave's
//   bf16x8 fragment load for (c,j) is one fully-coalesced 1 KB read.
// vt columns are sigma-permuted key positions: pos p holds key
//   u = (p&3)*16 + (p>>2), matching attn's P store order.
// attn v15 = v9 (best base: pairs {y,127-y}, 512 blocks x 4 waves,
// barrier-free, direct loads) + ENFORCED load pipelining:
//   - V(cur) loaded at body top (use ~400cyc later, covered by QK+softmax)
//   - K(next) issued in body (use next body, covered)
//   - __builtin_amdgcn_sched_barrier(0) after the load block: the compiler
//     CANNOT sink these loads to their uses (v11 failed exactly there:
//     VGPR=124 proved the k/v buffers were never held in registers).
// Only K double-buffered (k0/k1) + single V buffer: ~200 VGPR <= 256,
// keeps 2 waves/SIMD at launch_bounds(256,2). v12-v14 lessons: never
// request >2 waves/EU (allocator clamps to 64 VGPR and spills); wave
// count 8 vs 16 per CU is NOT the attn bottleneck (v14: 45.7us).

typedef __attribute__((ext_vector_type(8))) __bf16 bf16x8;
typedef __attribute__((ext_vector_type(4))) float f32x4;

#define S_LEN 2048
#define DIMN  2048
#define NH    32
#define NKV   8
#define HD    64
#define QKVF  3072

struct DoPair { static constexpr bool value = true; };
struct OnlyB  { static constexpr bool value = false; };

__device__ __forceinline__ ushort f2bf(float f) {
  union { float f; unsigned u; } v; v.f = f;
  unsigned r = v.u + 0x7fffu + ((v.u >> 16) & 1u);
  return (ushort)(r >> 16);
}
__device__ __forceinline__ unsigned pack_bf2_rz(float a, float b) {
  union { float f; unsigned u; } va, vb; va.f = a; vb.f = b;
  return (va.u >> 16) | (vb.u & 0xffff0000u);
}
__device__ __forceinline__ float bf2f(ushort u) {
  union { unsigned u; float f; } v; v.u = ((unsigned)u) << 16;
  return v.f;
}
__device__ __forceinline__ void gld_lds16(const void* g, void* l) {
  __builtin_amdgcn_global_load_lds(
      (const __attribute__((address_space(1))) unsigned int*)g,
      (__attribute__((address_space(3))) unsigned int*)l, 16, 0, 0);
}

// ---------------- f32 -> bf16 conversion (x, [wq;wk;wv], wo) ----------------
__global__ __launch_bounds__(256) void convert_all(
    const float* __restrict__ x, const float* __restrict__ wq,
    const float* __restrict__ wk, const float* __restrict__ wv,
    const float* __restrict__ wo, ushort* __restrict__ xb,
    ushort* __restrict__ wqkvb, ushort* __restrict__ wob) {
  const size_t NX = 4u * 1024 * 1024;
  const size_t NK = 1024 * 1024;
  size_t idx = ((size_t)blockIdx.x * 256 + threadIdx.x) * 4;
  const float* src; ushort* dst;
  if (idx < NX)                { src = x  + idx;                  dst = xb + idx; }
  else if (idx < 2 * NX)       { src = wq + (idx - NX);           dst = wqkvb + (idx - NX); }
  else if (idx < 2 * NX + NK)  { src = wk + (idx - 2 * NX);       dst = wqkvb + NX + (idx - 2 * NX); }
  else if (idx < 2 * NX + 2*NK){ src = wv + (idx - 2 * NX - NK);  dst = wqkvb + NX + NK + (idx - 2 * NX - NK); }
  else                         { src = wo + (idx - 2 * NX - 2*NK);dst = wob + (idx - 2 * NX - 2 * NK); }
  float4 v = *(const float4*)src;
  ushort4 o; o.x = f2bf(v.x); o.y = f2bf(v.y); o.z = f2bf(v.z); o.w = f2bf(v.w);
  *(ushort4*)dst = o;
}

// ---------------- GEMM: dbuf LDS + XOR bank swizzle, tile (BM x BN) ---------
// Balanced grids: 512 blocks = exactly 2/CU, dbuf LDS < 64 KB (2-block
// residency). qkv: 128x96 (56 KB). wo: 64x128 (48 KB).
template <int OUT_BF16, int BM, int BN>
__global__ __launch_bounds__(256) void gemm_bt(
    const ushort* __restrict__ A, const ushort* __restrict__ B,
    void* __restrict__ Cv, int M, int N, int K) {
  constexpr int IB = BM / 32;
  constexpr int JB = BN / 32;
  constexpr int NGA = BM / 8;
  constexpr int GPW = (BM + BN) / 32;
  __shared__ __align__(16) ushort As[2][BM * 64];
  __shared__ __align__(16) ushort Bs[2][BN * 64];
  const int n0 = blockIdx.x * BN, m0 = blockIdx.y * BM;
  const int t = threadIdx.x;
  const int lane = t & 63, wave = t >> 6;
  const int wm = (wave >> 1) * (BM / 2), wn = (wave & 1) * (BN / 2);
  const int col = lane & 15, quad = lane >> 4;
  const int sw = col & 7;
  const int lrow = lane >> 3;
  const int scol = ((lane & 7) ^ lrow) * 8;
  f32x4 acc[IB][JB] = {};

  auto stage = [&](int b, int kk) {
#pragma unroll
    for (int c = 0; c < GPW; ++c) {
      int g = wave * GPW + c;
      if (g < NGA)
        gld_lds16(&A[(size_t)(m0 + g * 8 + lrow) * K + kk + scol], &As[b][g * 8 * 64]);
      else
        gld_lds16(&B[(size_t)(n0 + (g - NGA) * 8 + lrow) * K + kk + scol],
                  &Bs[b][(g - NGA) * 8 * 64]);
    }
  };

  stage(0, 0);
  __syncthreads();
  for (int kk = 0; kk < K; kk += 64) {
    const int b = (kk >> 6) & 1;
    if (kk + 64 < K) stage(b ^ 1, kk + 64);
#pragma unroll
    for (int c = 0; c < 2; ++c) {
      const int chs = ((c * 4 + quad) ^ sw) * 8;
      bf16x8 af[IB], bfr[JB];
#pragma unroll
      for (int i = 0; i < IB; ++i)
        af[i] = *(const bf16x8*)&As[b][(wm + i * 16 + col) * 64 + chs];
#pragma unroll
      for (int j = 0; j < JB; ++j)
        bfr[j] = *(const bf16x8*)&Bs[b][(wn + j * 16 + col) * 64 + chs];
#pragma unroll
      for (int i = 0; i < IB; ++i)
#pragma unroll
        for (int j = 0; j < JB; ++j)
          acc[i][j] = __builtin_amdgcn_mfma_f32_16x16x32_bf16(af[i], bfr[j], acc[i][j], 0, 0, 0);
    }
    __syncthreads();
  }
#pragma unroll
  for (int i = 0; i < IB; ++i)
#pragma unroll
    for (int r = 0; r < 4; ++r) {
      int m = m0 + wm + i * 16 + quad * 4 + r;
      if (OUT_BF16) {
        ushort* C = (ushort*)Cv;
#pragma unroll
        for (int j = 0; j < JB; ++j)
          C[(size_t)m * N + n0 + wn + j * 16 + col] = f2bf(acc[i][j][r]);
      } else {
        float* C = (float*)Cv;
#pragma unroll
        for (int j = 0; j < JB; ++j)
          C[(size_t)m * N + n0 + wn + j * 16 + col] = acc[i][j][r];
      }
    }
}

// ---------------- RoPE + layout ---------------------------------------------
__global__ __launch_bounds__(256) void rope_layout(
    const ushort* __restrict__ qkv, const float* __restrict__ fc,
    const float* __restrict__ fs, ushort* __restrict__ qb,
    ushort* __restrict__ kb, ushort* __restrict__ vt) {
  __shared__ ushort T[64][72];
  const int hh = blockIdx.x;
  const int s0 = blockIdx.y * 256;
  const int t = threadIdx.x;
  if (hh < 32) {
    ushort* dst = qb + (size_t)hh * S_LEN * 64;
    const float qs = 0.18033688011112042f;  // (1/8)*log2(e)
    const int sr = t >> 4, dc = (t & 15) * 4, i0 = (t & 15) * 2;
#pragma unroll 4
    for (int pass = 0; pass < 16; ++pass) {
      int s = s0 + pass * 16 + sr;
      ushort4 vv = *(const ushort4*)&qkv[(size_t)s * QKVF + hh * 64 + dc];
      float2 cc = *(const float2*)&fc[s * 32 + i0];
      float2 ss = *(const float2*)&fs[s * 32 + i0];
      float xr0 = bf2f(vv.x), xi0 = bf2f(vv.y), xr1 = bf2f(vv.z), xi1 = bf2f(vv.w);
      ushort4 ov;
      ov.x = f2bf((xr0 * cc.x - xi0 * ss.x) * qs); ov.y = f2bf((xr0 * ss.x + xi0 * cc.x) * qs);
      ov.z = f2bf((xr1 * cc.y - xi1 * ss.y) * qs); ov.w = f2bf((xr1 * ss.y + xi1 * cc.y) * qs);
      *(ushort4*)&dst[(size_t)s * 64 + dc] = ov;
    }
  } else if (hh < 40) {
    const int kh2 = hh - 32;
    const int sr8 = t >> 3;
    const int ch = t & 7;
#pragma unroll 2
    for (int pass = 0; pass < 8; ++pass) {
      int s = s0 + pass * 32 + sr8;
      ushort in[8], out[8];
      *(int4*)&in[0] = *(const int4*)&qkv[(size_t)s * QKVF + 2048 + kh2 * 64 + ch * 8];
      float4 cc = *(const float4*)&fc[s * 32 + ch * 4];
      float4 ss4 = *(const float4*)&fs[s * 32 + ch * 4];
      const float* cp = &cc.x; const float* sp = &ss4.x;
#pragma unroll
      for (int i = 0; i < 4; ++i) {
        float xr = bf2f(in[2 * i]), xi = bf2f(in[2 * i + 1]);
        out[2 * i]     = f2bf(xr * cp[i] - xi * sp[i]);
        out[2 * i + 1] = f2bf(xr * sp[i] + xi * cp[i]);
      }
      int r = s & 63, tile = s >> 6;
      // fragment order: p = (ch>>2)*4 + (r>>4), lane = (ch&3)*16 + (r&15)
      size_t pos = ((size_t)(kh2 * 32 + tile)) * 4096 +
                   ((size_t)(((ch >> 2) * 4 + (r >> 4)) * 64 + (ch & 3) * 16 + (r & 15))) * 8;
      *(int4*)&kb[pos] = *(const int4*)&out[0];
    }
  } else {
    const int vh = hh - 40;
    for (int sub = 0; sub < 4; ++sub) {
      int sb = s0 + sub * 64;
      int sr = t >> 2, dc = (t & 3) * 16;
      ushort tmp[16];
      *(int4*)&tmp[0] = *(const int4*)&qkv[(size_t)(sb + sr) * QKVF + 2560 + vh * 64 + dc];
      *(int4*)&tmp[8] = *(const int4*)&qkv[(size_t)(sb + sr) * QKVF + 2560 + vh * 64 + dc + 8];
      __syncthreads();
      const int pcol = ((sr & 15) << 2) | (sr >> 4);  // sigma: key sr -> position
#pragma unroll
      for (int k = 0; k < 16; ++k) T[dc + k][pcol] = tmp[k];
      __syncthreads();
      int d = t >> 2;
      int ch0 = (t & 3) * 2, ch1 = ch0 + 1;
      int tile = sb >> 6;
      size_t base = ((size_t)(vh * 32 + tile)) * 4096;
      // fragment order: p = (ch>>2)*4 + (d>>4), lane = (ch&3)*16 + (d&15)
      size_t p0 = base + ((size_t)(((ch0 >> 2) * 4 + (d >> 4)) * 64 + (ch0 & 3) * 16 + (d & 15))) * 8;
      size_t p1 = base + ((size_t)(((ch1 >> 2) * 4 + (d >> 4)) * 64 + (ch1 & 3) * 16 + (d & 15))) * 8;
      *(int4*)&vt[p0] = *(const int4*)&T[d][ch0 * 8];
      *(int4*)&vt[p1] = *(const int4*)&T[d][ch1 * 8];
    }
  }
}

// ---------------- Flash attention v15: v9 + sched_barrier-pinned prefetch ---
// Grid (8 kvh, 64 pairs) = 512 blocks = 2/CU, 8 waves/CU = 2/SIMD.
// Block y: strips sA=y (short), sB=127-y (long); ntA+ntB = 33..34 balanced.
// Per tile body: V(cur) loads + K(next) loads issued FIRST, then
// sched_barrier(0) pins them (no sinking), then QK/softmax/PV. K-latency
// hides under previous body's compute; V-latency under QK+softmax.
// Barrier-free; per-wave Ps in LDS (within-wave DS order).
__global__ __launch_bounds__(256, 2) void attn(
    const ushort* __restrict__ qbg, const ushort* __restrict__ kbg,
    const ushort* __restrict__ vtg, ushort* __restrict__ yb) {
  __shared__ __align__(16) ushort Ps[4][2][16][64];  // [wave][strip][row][swz]
  const int kvh = blockIdx.x;
  const int y = blockIdx.y;
  const int sA = y, sB = 127 - y;
  const int ntA = (sA >> 2) + 1;
  const int ntB = (sB >> 2) + 1;
  const int wave = threadIdx.x >> 6;
  const int lane = threadIdx.x & 63;
  const int col = lane & 15, quad = lane >> 4;
  const int h = kvh * 4 + wave;
  const ushort* qh = qbg + (size_t)h * S_LEN * HD;
  const ushort* kbase = kbg + (size_t)kvh * 32 * 4096;
  const ushort* vbase = vtg + (size_t)kvh * 32 * 4096;

  const int q0A = sA * 16, q0B = sB * 16;
  bf16x8 qfA[2], qfB[2];
  qfA[0] = *(const bf16x8*)&qh[(size_t)(q0A + col) * HD + quad * 8];
  qfA[1] = *(const bf16x8*)&qh[(size_t)(q0A + col) * HD + 32 + quad * 8];
  qfB[0] = *(const bf16x8*)&qh[(size_t)(q0B + col) * HD + quad * 8];
  qfB[1] = *(const bf16x8*)&qh[(size_t)(q0B + col) * HD + 32 + quad * 8];
  float lA[4] = {}, lB[4] = {};
  f32x4 oA[4] = {}, oB[4] = {};

  bf16x8 k0[8], k1[8];

  auto loadK = [&](bf16x8 (&kf)[8], int t) {
    const ushort* kt = kbase + (size_t)t * 4096;
#pragma unroll
    for (int p = 0; p < 8; ++p) kf[p] = *(const bf16x8*)&kt[(p * 64 + lane) * 8];
  };

  auto body = [&](bf16x8 (&kfc)[8], bf16x8 (&kfn)[8], int t) {
    const bool doA = (t < ntA);
    const bool maskA = (t == ntA - 1);
    const bool maskB = (t == ntB - 1);
    // ---- load block: V(cur) + K(next); pinned by sched_barrier below ----
    bf16x8 vf[8];
    const ushort* vtt = vbase + (size_t)t * 4096;
#pragma unroll
    for (int p = 0; p < 8; ++p) vf[p] = *(const bf16x8*)&vtt[(p * 64 + lane) * 8];
    if (t + 1 < ntB) loadK(kfn, t + 1);
    __builtin_amdgcn_sched_barrier(0);  // forbid sinking loads into compute
    // ---- compute on current tile ----
    f32x4 scA[4] = {}, scB[4] = {};
#pragma unroll
    for (int c = 0; c < 2; ++c)
#pragma unroll
      for (int j = 0; j < 4; ++j)
        scB[j] = __builtin_amdgcn_mfma_f32_16x16x32_bf16(qfB[c], kfc[c * 4 + j], scB[j], 0, 0, 0);
    if (doA) {
#pragma unroll
      for (int c = 0; c < 2; ++c)
#pragma unroll
        for (int j = 0; j < 4; ++j)
          scA[j] = __builtin_amdgcn_mfma_f32_16x16x32_bf16(qfA[c], kfc[c * 4 + j], scA[j], 0, 0, 0);
    }
#pragma unroll
    for (int r = 0; r < 4; ++r) {
      const int prow = quad * 4 + r;
      const int psw = (((col >> 1) ^ (prow & 7)) << 3) + ((col & 1) << 2);
      const int rowq = q0B + prow;
      float pr[4];
#pragma unroll
      for (int j = 0; j < 4; ++j) {
        float e = __builtin_amdgcn_exp2f(scB[j][r]);
        if (maskB) e = (t * 64 + j * 16 + col > rowq) ? 0.f : e;
        pr[j] = e;
      }
      lB[r] += (pr[0] + pr[1]) + (pr[2] + pr[3]);
      uint2 pk;
      pk.x = pack_bf2_rz(pr[0], pr[1]);
      pk.y = pack_bf2_rz(pr[2], pr[3]);
      *(uint2*)&Ps[wave][1][prow][psw] = pk;
    }
    if (doA) {
#pragma unroll
      for (int r = 0; r < 4; ++r) {
        const int prow = quad * 4 + r;
        const int psw = (((col >> 1) ^ (prow & 7)) << 3) + ((col & 1) << 2);
        const int rowq = q0A + prow;
        float pr[4];
#pragma unroll
        for (int j = 0; j < 4; ++j) {
          float e = __builtin_amdgcn_exp2f(scA[j][r]);
          if (maskA) e = (t * 64 + j * 16 + col > rowq) ? 0.f : e;
          pr[j] = e;
        }
        lA[r] += (pr[0] + pr[1]) + (pr[2] + pr[3]);
        uint2 pk;
        pk.x = pack_bf2_rz(pr[0], pr[1]);
        pk.y = pack_bf2_rz(pr[2], pr[3]);
        *(uint2*)&Ps[wave][0][prow][psw] = pk;
      }
    }
#pragma unroll
    for (int c = 0; c < 2; ++c) {
      const int psr = ((c * 4 + quad) ^ (col & 7)) * 8;
      bf16x8 pfB = *(const bf16x8*)&Ps[wave][1][col][psr];
#pragma unroll
      for (int db = 0; db < 4; ++db)
        oB[db] = __builtin_amdgcn_mfma_f32_16x16x32_bf16(pfB, vf[c * 4 + db], oB[db], 0, 0, 0);
    }
    if (doA) {
#pragma unroll
      for (int c = 0; c < 2; ++c) {
        const int psr = ((c * 4 + quad) ^ (col & 7)) * 8;
        bf16x8 pfA = *(const bf16x8*)&Ps[wave][0][col][psr];
#pragma unroll
        for (int db = 0; db < 4; ++db)
          oA[db] = __builtin_amdgcn_mfma_f32_16x16x32_bf16(pfA, vf[c * 4 + db], oA[db], 0, 0, 0);
      }
    }
  };

  loadK(k0, 0);
  for (int t = 0; t < ntB;) {
    body(k0, k1, t);
    ++t;
    if (t >= ntB) break;
    body(k1, k0, t);
    ++t;
  }

  auto write_out = [&](const f32x4 (&o)[4], const float (&l)[4], int q0) {
#pragma unroll
    for (int r = 0; r < 4; ++r) {
      float ls = l[r];
      ls += __shfl_xor(ls, 1);
      ls += __shfl_xor(ls, 2);
      ls += __shfl_xor(ls, 4);
      ls += __shfl_xor(ls, 8);
      float inv = 1.0f / ls;
      int rowq = q0 + quad * 4 + r;
#pragma unroll
      for (int db = 0; db < 4; ++db)
        yb[(size_t)rowq * (NH * HD) + h * HD + db * 16 + col] = f2bf(o[db][r] * inv);
    }
  };
  write_out(oA, lA, q0A);
  write_out(oB, lB, q0B);
}

extern "C" void kernel_launch(void* const* d_in, const int* in_sizes, int n_in,
                              void* d_out, int out_size, void* d_ws, size_t ws_size,
                              hipStream_t stream) {
  (void)in_sizes; (void)n_in; (void)out_size; (void)ws_size;
  const float* x  = (const float*)d_in[0];
  const float* fc = (const float*)d_in[1];
  const float* fs = (const float*)d_in[2];
  const float* wq = (const float*)d_in[4];
  const float* wk = (const float*)d_in[5];
  const float* wv = (const float*)d_in[6];
  const float* wo = (const float*)d_in[7];
  ushort* w = (ushort*)d_ws;
  const size_t M1 = 1024 * 1024;
  ushort* xb    = w;
  ushort* wqkvb = w + 4 * M1;
  ushort* wob   = w + 10 * M1;
  ushort* qkvb  = w + 14 * M1;
  ushort* qb    = w + 20 * M1;
  ushort* kb    = w + 24 * M1;
  ushort* vt    = w + 25 * M1;
  ushort* yb    = w + 26 * M1;

  convert_all<<<14336, 256, 0, stream>>>(x, wq, wk, wv, wo, xb, wqkvb, wob);
  gemm_bt<1, 128, 96><<<dim3(QKVF / 96, S_LEN / 128), 256, 0, stream>>>(xb, wqkvb, qkvb, S_LEN, QKVF, DIMN);
  rope_layout<<<dim3(48, 8), 256, 0, stream>>>(qkvb, fc, fs, qb, kb, vt);
  attn<<<dim3(NKV, 64), 256, 0, stream>>>(qb, kb, vt, yb);
  gemm_bt<0, 64, 128><<<dim3(DIMN / 128, S_LEN / 64), 256, 0, stream>>>(yb, wob, d_out, S_LEN, DIMN, NH * HD);
}